// Round 12
// baseline (115.129 us; speedup 1.0000x reference)
//
#include <hip/hip_runtime.h>
#include <hip/hip_bf16.h>
#include <math.h>

#define N_ 4096
#define B_ 4
#define C_ 64
#define MT 64                 // m-columns per attn block
#define NT 128                // n per step
#define SPLITN 4              // n-splits (partials added; no max needed)
#define HSEG (N_ / SPLITN)    // 1024
#define STEPS (HSEG / NT)     // 8
#define QSCALE 0.1803368801111137f   // 0.125 * log2(e), folded into Wq

typedef __attribute__((ext_vector_type(8))) short bf16x8;
typedef __attribute__((ext_vector_type(4))) float f32x4;
#define MFMA(a, b, c) __builtin_amdgcn_mfma_f32_16x16x32_bf16(a, b, c, 0, 0, 0)

#if __has_builtin(__builtin_amdgcn_exp2f)
#define EXP2(x) __builtin_amdgcn_exp2f(x)
#else
#define EXP2(x) __expf((x) * 0.6931471805599453f)
#endif

static __device__ __forceinline__ uint hi_bits(float f) {
    return (__float_as_uint(f) + 0x8000u) >> 16;
}
static __device__ __forceinline__ float hi_val(float f) {
    return __uint_as_float((__float_as_uint(f) + 0x8000u) & 0xFFFF0000u);
}

// ---------------------------------------------------------------------------
// MFMA QKV projection -> FRAGMENT-MAJOR layouts (unchanged from R11).
//  Qf/Kf: [B][N/16][ks=2][lane=64][8] ; Vf: [B][ot=4][N/32][lane=64][8]
// ---------------------------------------------------------------------------
__global__ __launch_bounds__(256) void qkv_mfma(
    const float* __restrict__ x,  const float* __restrict__ Wq,
    const float* __restrict__ Wk, const float* __restrict__ Wv,
    ushort* __restrict__ Qf, ushort* __restrict__ Kf, ushort* __restrict__ Vf)
{
    __shared__ float xs[C_][33];

    const int b   = blockIdx.x / (N_ / 32);
    const int n0  = (blockIdx.x % (N_ / 32)) * 32;
    const int tid = threadIdx.x;
    const int w   = tid >> 6;
    const int l   = tid & 63;
    const int lr  = l & 15;
    const int lg  = l >> 4;

    #pragma unroll
    for (int it = 0; it < 2; ++it) {
        const int i = tid + it * 256;
        const int row = i >> 3, q = i & 7;
        const float4 a = *(const float4*)(x + ((size_t)b * C_ + row) * N_ + n0 + q * 4);
        xs[row][q * 4 + 0] = a.x; xs[row][q * 4 + 1] = a.y;
        xs[row][q * 4 + 2] = a.z; xs[row][q * 4 + 3] = a.w;
    }

    bf16x8 wh[3][2], wl[3][2];
    #pragma unroll
    for (int i = 0; i < 3; ++i) {
        const int rt  = w * 3 + i;
        const int mat = rt >> 2;          // 0=q 1=k 2=v
        const int dt  = rt & 3;
        const float* __restrict__ W = (mat == 0) ? Wq : ((mat == 1) ? Wk : Wv);
        const float scale = (mat == 0) ? QSCALE : 1.0f;
        #pragma unroll
        for (int ks = 0; ks < 2; ++ks) {
            const float4* p = (const float4*)(W + (dt * 16 + lr) * C_ + ks * 32 + lg * 8);
            float4 f0 = p[0], f1 = p[1];
            float v[8] = {f0.x, f0.y, f0.z, f0.w, f1.x, f1.y, f1.z, f1.w};
            bf16x8 ht, lt;
            #pragma unroll
            for (int j = 0; j < 8; ++j) {
                const float f = v[j] * scale;
                const float h = hi_val(f);
                ht[j] = (short)(__float_as_uint(h) >> 16);
                lt[j] = (short)hi_bits(f - h);
            }
            wh[i][ks] = ht; wl[i][ks] = lt;
        }
    }
    __syncthreads();

    #pragma unroll
    for (int nt = 0; nt < 2; ++nt) {
        bf16x8 xh[2], xl[2];
        #pragma unroll
        for (int ks = 0; ks < 2; ++ks) {
            bf16x8 ht, lt;
            #pragma unroll
            for (int j = 0; j < 8; ++j) {
                const float f = xs[ks * 32 + lg * 8 + j][nt * 16 + lr];
                const float h = hi_val(f);
                ht[j] = (short)(__float_as_uint(h) >> 16);
                lt[j] = (short)hi_bits(f - h);
            }
            xh[ks] = ht; xl[ks] = lt;
        }

        #pragma unroll
        for (int i = 0; i < 3; ++i) {
            const int rt  = w * 3 + i;
            const int mat = rt >> 2;
            const int dt  = rt & 3;
            f32x4 acc = (f32x4){0.f, 0.f, 0.f, 0.f};
            if (mat < 2) {              // C[row=d][col=n]
                #pragma unroll
                for (int ks = 0; ks < 2; ++ks) {
                    acc = MFMA(wh[i][ks], xh[ks], acc);
                    acc = MFMA(wh[i][ks], xl[ks], acc);
                    acc = MFMA(wl[i][ks], xh[ks], acc);
                }
                const uint2 pk = make_uint2((hi_bits(acc[1]) << 16) | hi_bits(acc[0]),
                                            (hi_bits(acc[3]) << 16) | hi_bits(acc[2]));
                ushort* __restrict__ H = mat ? Kf : Qf;
                const int tile = (n0 >> 4) + nt;
                const int ksq  = dt >> 1;
                const int lga  = (dt & 1) * 2 + (lg >> 1);
                const int j0   = (lg & 1) * 4;
                const size_t addr = (((size_t)b * (N_ / 16) + tile) * 2 + ksq) * 512
                                  + (lga * 16 + lr) * 8 + j0;
                *(uint2*)(H + addr) = pk;
            } else {                    // C[row=n][col=o]
                #pragma unroll
                for (int ks = 0; ks < 2; ++ks) {
                    acc = MFMA(xh[ks], wh[i][ks], acc);
                    acc = MFMA(xl[ks], wh[i][ks], acc);
                    acc = MFMA(xh[ks], wl[i][ks], acc);
                }
                const uint2 pk = make_uint2((hi_bits(acc[1]) << 16) | hi_bits(acc[0]),
                                            (hi_bits(acc[3]) << 16) | hi_bits(acc[2]));
                const int nc  = n0 >> 5;
                const int lga = nt * 2 + (lg >> 1);
                const int j0  = (lg & 1) * 4;
                const size_t addr = (((size_t)b * 4 + dt) * (N_ / 32) + nc) * 512
                                  + (lga * 16 + lr) * 8 + j0;
                *(uint2*)(Vf + addr) = pk;
            }
        }
    }
}

// ---------------------------------------------------------------------------
// Attention partial (R11 structure, SPLITN=4): block = 64 m-cols, 4 waves,
// one n-quarter. 1024 blocks -> 4 blocks/CU (LDS 33KB x4 = 132KB < 160KB),
// 4 waves/SIMD TLP. All fragment loads contiguous 1-KB wave reads.
// ---------------------------------------------------------------------------
__global__ __launch_bounds__(256, 4) void attn_mfma(
    const ushort* __restrict__ Qf, const ushort* __restrict__ Kf,
    const ushort* __restrict__ Vf,
    float* __restrict__ pacc, float* __restrict__ pden)
{
    __shared__ ushort Em[2][MT * NT];     // 32 KB, rotation-swizzled
    __shared__ float red[4][MT];

    // XCD pinning: bid&7 = (b, p-low); p-high from bit 3; mt = bid>>4
    const int bid = blockIdx.x;
    const int xcd = bid & 7;
    const int b   = xcd >> 1;
    const int p   = (xcd & 1) + 2 * ((bid >> 3) & 1);
    const int mt  = bid >> 4;             // 0..63
    const int tid = threadIdx.x;
    const int w   = tid >> 6;
    const int l   = tid & 63;
    const int lr  = l & 15;
    const int lg  = l >> 4;
    const int m0  = mt * MT;
    const int nG  = p * HSEG;

    // resident K B-frags: 8 contiguous 1-KB reads
    bf16x8 khf[4][2];
    #pragma unroll
    for (int f = 0; f < 4; ++f)
        #pragma unroll
        for (int ks = 0; ks < 2; ++ks)
            khf[f][ks] = *(const bf16x8*)(Kf + (((size_t)b * (N_ / 16) + (m0 >> 4) + f) * 2 + ks) * 512 + l * 8);

    f32x4 oacc[4];
    #pragma unroll
    for (int f = 0; f < 4; ++f) oacc[f] = (f32x4){0.f, 0.f, 0.f, 0.f};
    float den[4] = {0.f, 0.f, 0.f, 0.f};

    // Q A-frags for step 0 (wave's 32 n-rows = 2 tiles)
    bf16x8 qcur[2][2];
    #pragma unroll
    for (int nt2 = 0; nt2 < 2; ++nt2)
        #pragma unroll
        for (int ks = 0; ks < 2; ++ks)
            qcur[nt2][ks] = *(const bf16x8*)(Qf + (((size_t)b * (N_ / 16) + (nG >> 4) + w * 2 + nt2) * 2 + ks) * 512 + l * 8);

    for (int t = 0; t < STEPS; ++t) {
        const int nbase = nG + t * NT;
        const int buf   = t & 1;

        // V A-frags — 4 contiguous 1-KB reads, issued early
        bf16x8 vh[4];
        #pragma unroll
        for (int ks = 0; ks < 4; ++ks)
            vh[ks] = *(const bf16x8*)(Vf + (((size_t)b * 4 + w) * (N_ / 32) + (nbase >> 5) + ks) * 512 + l * 8);

        // S = Q·K (32 n-rows x 64 m)
        f32x4 s2[2][4];
        #pragma unroll
        for (int nt2 = 0; nt2 < 2; ++nt2)
            #pragma unroll
            for (int f = 0; f < 4; ++f) s2[nt2][f] = (f32x4){0.f, 0.f, 0.f, 0.f};
        __builtin_amdgcn_s_setprio(1);
        #pragma unroll
        for (int ks = 0; ks < 2; ++ks)
            #pragma unroll
            for (int nt2 = 0; nt2 < 2; ++nt2)
                #pragma unroll
                for (int f = 0; f < 4; ++f)
                    s2[nt2][f] = MFMA(qcur[nt2][ks], khf[f][ks], s2[nt2][f]);
        __builtin_amdgcn_s_setprio(0);

        // prefetch next step's Q
        const int tn = (t + 1 < STEPS) ? (t + 1) : t;
        bf16x8 qnext[2][2];
        #pragma unroll
        for (int nt2 = 0; nt2 < 2; ++nt2)
            #pragma unroll
            for (int ks = 0; ks < 2; ++ks)
                qnext[nt2][ks] = *(const bf16x8*)(Qf + (((size_t)b * (N_ / 16) + (nG >> 4) + tn * 8 + w * 2 + nt2) * 2 + ks) * 512 + l * 8);

        // E = exp2(s) -> bf16, den accumulate, swizzled LDS write
        #pragma unroll
        for (int nt2 = 0; nt2 < 2; ++nt2)
            #pragma unroll
            for (int f = 0; f < 4; ++f) {
                const float e0 = EXP2(s2[nt2][f][0]);
                const float e1 = EXP2(s2[nt2][f][1]);
                const float e2 = EXP2(s2[nt2][f][2]);
                const float e3 = EXP2(s2[nt2][f][3]);
                den[f] += (e0 + e1) + (e2 + e3);
                const uint u0 = __float_as_uint(e0) + 0x8000u;
                const uint u1 = __float_as_uint(e1) + 0x8000u;
                const uint u2 = __float_as_uint(e2) + 0x8000u;
                const uint u3 = __float_as_uint(e3) + 0x8000u;
                const int row = f * 16 + lr;
                const int g   = w * 4 + nt2 * 2 + (lg >> 1);
                *(uint2*)&Em[buf][row * NT + (((g + row) & 15) << 3) + ((lg & 1) << 2)] =
                    make_uint2((u1 & 0xFFFF0000u) | (u0 >> 16), (u3 & 0xFFFF0000u) | (u2 >> 16));
            }
        __syncthreads();

        // PV: out[o][m] += V[o][n] * E[n][m]
        __builtin_amdgcn_s_setprio(1);
        #pragma unroll
        for (int ks = 0; ks < 4; ++ks)
            #pragma unroll
            for (int f = 0; f < 4; ++f) {
                const int row = f * 16 + lr;
                const bf16x8 eb = *(const bf16x8*)&Em[buf][row * NT + (((ks * 4 + lg + row) & 15) << 3)];
                oacc[f] = MFMA(vh[ks], eb, oacc[f]);
            }
        __builtin_amdgcn_s_setprio(0);

        #pragma unroll
        for (int nt2 = 0; nt2 < 2; ++nt2) {
            qcur[nt2][0] = qnext[nt2][0];
            qcur[nt2][1] = qnext[nt2][1];
        }
    }

    // ---- epilogue (R4-verified partial write) ----
    #pragma unroll
    for (int f = 0; f < 4; ++f) {
        den[f] += __shfl_xor(den[f], 16);
        den[f] += __shfl_xor(den[f], 32);
    }
    __syncthreads();
    if (lg == 0)
        #pragma unroll
        for (int f = 0; f < 4; ++f) red[w][f * 16 + lr] = den[f];
    __syncthreads();

    const int pb = b * SPLITN + p;
    if (w == 0 && lg == 0)
        #pragma unroll
        for (int f = 0; f < 4; ++f)
            pden[(size_t)pb * N_ + m0 + f * 16 + lr] =
                red[0][f * 16 + lr] + red[1][f * 16 + lr] + red[2][f * 16 + lr] + red[3][f * 16 + lr];

    #pragma unroll
    for (int f = 0; f < 4; ++f)
        #pragma unroll
        for (int r = 0; r < 4; ++r) {
            const int o = w * 16 + lg * 4 + r;
            pacc[((size_t)pb * C_ + o) * N_ + m0 + f * 16 + lr] = oacc[f][r];
        }
}

// ---------------------------------------------------------------------------
// Combine: out = sum_p pacc / sum_p pden (float4 along m), SPLITN=4
// ---------------------------------------------------------------------------
__global__ __launch_bounds__(256) void combine_kernel(
    const float* __restrict__ pacc, const float* __restrict__ pden,
    float* __restrict__ out)
{
    const int idx = blockIdx.x * 256 + threadIdx.x;
    const int m4 = idx & (N_ / 4 - 1);
    const int o  = (idx >> 10) & 63;
    const int b  = idx >> 16;

    float4 s = make_float4(0.f, 0.f, 0.f, 0.f);
    float4 d = make_float4(0.f, 0.f, 0.f, 0.f);
    #pragma unroll
    for (int p = 0; p < SPLITN; ++p) {
        const float4 a = *(const float4*)(pacc + (((size_t)(b * SPLITN + p)) * C_ + o) * N_ + m4 * 4);
        const float4 e = *(const float4*)(pden + ((size_t)(b * SPLITN + p)) * N_ + m4 * 4);
        s.x += a.x; s.y += a.y; s.z += a.z; s.w += a.w;
        d.x += e.x; d.y += e.y; d.z += e.z; d.w += e.w;
    }
    *(float4*)(out + ((size_t)b * C_ + o) * N_ + m4 * 4) =
        make_float4(s.x / d.x, s.y / d.y, s.z / d.z, s.w / d.w);
}

// ---------------------------------------------------------------------------
extern "C" void kernel_launch(void* const* d_in, const int* in_sizes, int n_in,
                              void* d_out, int out_size, void* d_ws, size_t ws_size,
                              hipStream_t stream)
{
    const float* x  = (const float*)d_in[0];
    const float* Wq = (const float*)d_in[1];
    const float* Wk = (const float*)d_in[2];
    const float* Wv = (const float*)d_in[3];
    float* out = (float*)d_out;

    const size_t NE = (size_t)B_ * N_ * C_;   // 1M elements per bf16 array
    ushort* Qf = (ushort*)d_ws;
    ushort* Kf = Qf + NE;
    ushort* Vf = Kf + NE;
    float* pacc = (float*)(Vf + NE);                       // [B*4][64][N] = 16 MB
    float* pden = pacc + (size_t)B_ * SPLITN * C_ * N_;    // [B*4][N]

    qkv_mfma<<<B_ * (N_ / 32), 256, 0, stream>>>(x, Wq, Wk, Wv, Qf, Kf, Vf);
    attn_mfma<<<B_ * (N_ / MT) * SPLITN, 256, 0, stream>>>(Qf, Kf, Vf, pacc, pden);
    combine_kernel<<<B_ * C_ * N_ / 1024, 256, 0, stream>>>(pacc, pden, out);
}